// Round 8
// baseline (5684.230 us; speedup 1.0000x reference)
//
#include <hip/hip_runtime.h>
#include <math.h>

// ---------------------------------------------------------------------------
// LSTM encoder-decoder, 3-term bf16 MFMA (hi/lo split), persistent kernel.
// 8 XCD-local groups (bid&7), 32 blocks x 512 thr each, own 32 batch rows.
// Per enc step: each block computes a 64-col z slice -> ONE fan-32 barrier ->
// EVERY block redundantly computes the full softmax update for all 32 rows,
// keeping h in LDS (XOR-swizzled; h never crosses blocks). z double-buffered
// by parity (no 2nd barrier). Decoder: same pattern, dir-split fan-16.
// Barrier: r7's monotonic cnt/gen, relaxed RMW arrive + relaxed LOAD poll +
// buffer_inv sc0 (L1-only) + timeout guard.
// ---------------------------------------------------------------------------

typedef __attribute__((ext_vector_type(8))) short bf16x8;
typedef __attribute__((ext_vector_type(8))) unsigned short u16x8;
typedef __attribute__((ext_vector_type(4))) float f32x4;

// ws layout (float offsets)
#define OFS_Z      0u          // 2 x 256*2048 f32 (parity dbuf)
#define OFS_XW     1048576u    // 256*2048 f32
#define OFS_HSEQ   1572864u    // 256*64*512 bf16 (=4194304 f)
#define OFS_BENCH  5767168u    // 72*2048*8 bf16 packed
#define OFS_BENCL  6356992u
#define OFS_BDKH   6946816u    // 64*2048*8 bf16 packed
#define OFS_BDKL   7471104u
#define OFS_BDUH   7995392u    // 32*2048*8 bf16 packed
#define OFS_BDUL   8257536u
#define OFS_BAR    8519680u    // 2048 u32: group g at [g*256]: encCnt+0,
                               //  encGen+32, d0Cnt+64, d0Gen+96, d1Cnt+128, d1Gen+160
#define WS_FLOATS  8521728u    // ~34.1 MB

__device__ __forceinline__ unsigned short bf_hi(float f) {
    union { float f; unsigned u; } v; v.f = f;
    unsigned r = v.u + 0x7fffu + ((v.u >> 16) & 1u);
    return (unsigned short)(r >> 16);
}
__device__ __forceinline__ float bf2f(unsigned short h) {
    union { unsigned u; float f; } v; v.u = ((unsigned)h) << 16;
    return v.f;
}
__device__ __forceinline__ void split2(float f, unsigned short& hi, unsigned short& lo) {
    hi = bf_hi(f);
    lo = bf_hi(f - bf2f(hi));
}
__device__ __forceinline__ float sigm(float x) { return 1.0f / (1.0f + __expf(-x)); }

// ---- XCD-local barrier (monotonic; r7-proven) -----------------------------
__device__ __forceinline__ void gbar2(unsigned* cnt, unsigned* gen,
                                      unsigned fan, int target) {
    asm volatile("s_waitcnt vmcnt(0) lgkmcnt(0)" ::: "memory");
    __syncthreads();
    if (threadIdx.x == 0) {
        const unsigned old = __hip_atomic_fetch_add(cnt, 1u, __ATOMIC_RELAXED,
                                                    __HIP_MEMORY_SCOPE_AGENT);
        if (old == (unsigned)target * fan - 1u) {
            __hip_atomic_fetch_add(gen, 1u, __ATOMIC_RELAXED,
                                   __HIP_MEMORY_SCOPE_AGENT);
        } else {
            const long long t0 = clock64();
            while ((int)__hip_atomic_load(gen, __ATOMIC_RELAXED,
                                          __HIP_MEMORY_SCOPE_AGENT) < target) {
                __builtin_amdgcn_s_sleep(4);
                asm volatile("buffer_inv sc0" ::: "memory");
                if (clock64() - t0 > 16000000LL) break;   // deadlock guard only
            }
        }
        asm volatile("buffer_inv sc0" ::: "memory");      // L1 invalidate only
    }
    __syncthreads();
}

// 16-lane-span reductions (rows = 16 consecutive lanes; xor masks stay in span)
__device__ __forceinline__ float red16max(float v) {
    #pragma unroll
    for (int m = 8; m; m >>= 1) v = fmaxf(v, __shfl_xor(v, m, 64));
    return v;
}
__device__ __forceinline__ float red16sum(float v) {
    #pragma unroll
    for (int m = 8; m; m >>= 1) v += __shfl_xor(v, m, 64);
    return v;
}

// ---------------------------------------------------------------------------
// weight pack: fp32 -> bf16 hi/lo, frag layout [k/8][n][8]
// MODE 0 also zero-initializes the 2048 barrier words (replay-safe).
// ---------------------------------------------------------------------------
template <int MODE>
__global__ __launch_bounds__(256) void pack_b(
    const float* __restrict__ S0, const float* __restrict__ S1,
    unsigned short* __restrict__ H, unsigned short* __restrict__ L,
    unsigned* __restrict__ bar)
{
    if (MODE == 0 && blockIdx.x < 8) bar[blockIdx.x * 256 + threadIdx.x] = 0u;
    const int idx = blockIdx.x * 256 + threadIdx.x;
    const int n = idx & 2047, kg = idx >> 11;
    u16x8 h8, l8;
    #pragma unroll
    for (int j = 0; j < 8; ++j) {
        const int k = kg * 8 + j;
        float v;
        if (MODE == 0) v = (k < 64) ? S0[(size_t)k * 2048 + n] : S1[(size_t)(k - 64) * 2048 + n];
        else           v = (n < 1024) ? S0[(size_t)k * 1024 + n] : S1[(size_t)k * 1024 + (n - 1024)];
        unsigned short hh, ll; split2(v, hh, ll);
        h8[j] = hh; l8[j] = ll;
    }
    *(u16x8*)(H + (size_t)idx * 8) = h8;
    *(u16x8*)(L + (size_t)idx * 8) = l8;
}

// ===========================================================================
// Persistent kernel. 256 blocks x 512 thr, LDS 64KB (capacity 2/CU -> slack).
// group g = bid&7 (XCD), slot w = bid>>3 (0..31, 64-col z slice).
// ===========================================================================
__global__ __launch_bounds__(512, 2) void lstm_all(
    const float* __restrict__ x, const float* __restrict__ encB,
    const float* __restrict__ dfB, const float* __restrict__ dbB,
    const float* __restrict__ dK, const float* __restrict__ dnB,
    float* __restrict__ out, float* __restrict__ ws)
{
    const int bid = blockIdx.x, tid = threadIdx.x;
    const int g = bid & 7, w = bid >> 3;          // group, slot 0..31
    const int lane = tid & 63, wid = tid >> 6;
    const int mh = wid & 1, nh = wid >> 1;        // 2 x 4 wave grid
    const int l16 = lane >> 4, lr = lane & 15;
    const int lrow = mh * 16 + lr;                // local A row 0..31
    const int grow = g * 32 + lrow;               // global batch row
    const int gcol = w * 64 + nh * 16 + lr;       // global z col 0..2047

    float* zb = ws + OFS_Z;
    float* xw = ws + OFS_XW;
    unsigned short* hseqb = (unsigned short*)(ws + OFS_HSEQ);
    const unsigned short* BeH = (const unsigned short*)(ws + OFS_BENCH);
    const unsigned short* BeL = (const unsigned short*)(ws + OFS_BENCL);
    const unsigned short* BkH = (const unsigned short*)(ws + OFS_BDKH);
    const unsigned short* BkL = (const unsigned short*)(ws + OFS_BDKL);
    const unsigned short* BuH = (const unsigned short*)(ws + OFS_BDUH);
    const unsigned short* BuL = (const unsigned short*)(ws + OFS_BDUL);
    unsigned* barg = (unsigned*)(ws + OFS_BAR) + g * 256;
    unsigned* encCnt = barg + 0;
    unsigned* encGen = barg + 32;
    int bcE = 0, bcD = 0;

    // h state in LDS: [32 rows][512 units] bf16 hi/lo, 16B-block XOR swizzle
    // phys byte = row*1024 + ((blk ^ (row&7))<<4), blk = unit>>3
    __shared__ __align__(16) unsigned short hH[16384];   // 32 KB
    __shared__ __align__(16) unsigned short hL[16384];   // 32 KB

    {   // zero h
        const uint4 z4{0u, 0u, 0u, 0u};
        for (int i = tid; i < 2048; i += 512) { ((uint4*)hH)[i] = z4; ((uint4*)hL)[i] = z4; }
    }
    __syncthreads();

    // update-phase thread ids
    const int urow = tid >> 4;                    // 0..31 (row)
    const int uch  = tid & 15;                    // 16 chunks per row

    const float encBias = encB[gcol];             // folded into z epilogue
    float c[32];
    #pragma unroll
    for (int j = 0; j < 32; ++j) c[j] = 0.f;

    // =====================================================================
    // encoder: 256 steps, ONE barrier per step
    // =====================================================================
    for (int t = 0; t < 256; ++t) {
        float* zc = zb + (unsigned)(t & 1) * 524288u;
        {   // ---- GEMM: z[32 rows][my 64 cols] = [x_t|h] @ Benc (K=576) ----
            f32x4 acc = {0.f, 0.f, 0.f, 0.f};
            #pragma unroll
            for (int kw = 0; kw < 18; ++kw) {
                bf16x8 a_h, a_l;
                const int kg = kw * 4 + l16;      // B row 0..71
                if (kw < 2) {                     // x slice, fp32 -> hi/lo inline
                    const float* xp = x + (size_t)grow * 16384 + t * 64 + kg * 8;
                    const float4 x0 = *(const float4*)xp;
                    const float4 x1 = *(const float4*)(xp + 4);
                    const float xs[8] = {x0.x, x0.y, x0.z, x0.w, x1.x, x1.y, x1.z, x1.w};
                    #pragma unroll
                    for (int j = 0; j < 8; ++j) {
                        unsigned short hh, ll; split2(xs[j], hh, ll);
                        a_h[j] = (short)hh; a_l[j] = (short)ll;
                    }
                } else {                          // h from LDS (swizzled)
                    const int kgh = kg - 8;       // 0..63
                    const int off = lrow * 1024 + ((kgh ^ (lrow & 7)) << 4);
                    a_h = *(const bf16x8*)((const char*)hH + off);
                    a_l = *(const bf16x8*)((const char*)hL + off);
                }
                const size_t bo = ((size_t)kg * 2048 + gcol) * 8;
                const bf16x8 b_h = *(const bf16x8*)(BeH + bo);
                const bf16x8 b_l = *(const bf16x8*)(BeL + bo);
                acc = __builtin_amdgcn_mfma_f32_16x16x32_bf16(a_h, b_h, acc, 0, 0, 0);
                acc = __builtin_amdgcn_mfma_f32_16x16x32_bf16(a_h, b_l, acc, 0, 0, 0);
                acc = __builtin_amdgcn_mfma_f32_16x16x32_bf16(a_l, b_h, acc, 0, 0, 0);
            }
            // C/D: col = lane&15, row = (lane>>4)*4 + r ; bias folded here
            float* zp = zc + (size_t)(g * 32 + mh * 16 + l16 * 4) * 2048 + gcol;
            #pragma unroll
            for (int r = 0; r < 4; ++r) zp[2048 * r] = acc[r] + encBias;
        }
        gbar2(encCnt, encGen, 32, ++bcE);

        // ---- redundant update: all blocks, all 32 rows; h stays in LDS ----
        {
            const float* zr = zc + (size_t)(g * 32 + urow) * 2048;
            const int u0 = uch * 32;
            float zgv[32]; float mx = -1e30f;
            #pragma unroll
            for (int jj = 0; jj < 8; ++jj) {
                const float4 v = *(const float4*)(zr + 1024 + u0 + jj * 4);
                zgv[jj*4+0] = v.x; zgv[jj*4+1] = v.y; zgv[jj*4+2] = v.z; zgv[jj*4+3] = v.w;
                mx = fmaxf(mx, fmaxf(fmaxf(v.x, v.y), fmaxf(v.z, v.w)));
            }
            mx = red16max(mx);
            float s = 0.f;
            #pragma unroll
            for (int j = 0; j < 32; ++j) { zgv[j] = __expf(zgv[j] - mx); s += zgv[j]; }
            const float inv = 1.0f / red16sum(s);

            float cmx = -1e30f;
            #pragma unroll
            for (int jj = 0; jj < 8; ++jj) {
                const float4 zi4 = *(const float4*)(zr + u0 + jj * 4);
                const float4 zf4 = *(const float4*)(zr + 512 + u0 + jj * 4);
                const float zi_[4] = {zi4.x, zi4.y, zi4.z, zi4.w};
                const float zf_[4] = {zf4.x, zf4.y, zf4.z, zf4.w};
                #pragma unroll
                for (int k = 0; k < 4; ++k) {
                    const int j = jj * 4 + k;
                    const float cv = sigm(zf_[k]) * c[j] + sigm(zi_[k]) * (zgv[j] * inv);
                    c[j] = cv; cmx = fmaxf(cmx, cv);
                }
            }
            cmx = red16max(cmx);
            float s2 = 0.f;
            #pragma unroll
            for (int j = 0; j < 32; ++j) s2 += __expf(c[j] - cmx);
            const float inv2 = 1.0f / red16sum(s2);

            #pragma unroll
            for (int jj = 0; jj < 8; ++jj) {
                const float4 zo4 = *(const float4*)(zr + 1536 + u0 + jj * 4);
                const float zo_[4] = {zo4.x, zo4.y, zo4.z, zo4.w};
                #pragma unroll
                for (int p2 = 0; p2 < 2; ++p2) {
                    const int j0 = jj * 4 + p2 * 2;
                    const float h0 = sigm(zo_[p2*2+0]) * __expf(c[j0]   - cmx) * inv2;
                    const float h1 = sigm(zo_[p2*2+1]) * __expf(c[j0+1] - cmx) * inv2;
                    unsigned short h0h, h0l, h1h, h1l;
                    split2(h0, h0h, h0l); split2(h1, h1h, h1l);
                    const int u = u0 + j0;
                    const int off = urow * 1024 + (((u >> 3) ^ (urow & 7)) << 4) + (u & 7) * 2;
                    *(unsigned*)((char*)hH + off) = (unsigned)h0h | ((unsigned)h1h << 16);
                    *(unsigned*)((char*)hL + off) = (unsigned)h0l | ((unsigned)h1l << 16);
                }
            }
        }
        __syncthreads();   // h writes visible to all waves before next GEMM
    }

    // =====================================================================
    // decoder input projection: xw[rows][my 64 cols] = Henc @ Bdk + bias
    // =====================================================================
    {
        f32x4 acc = {0.f, 0.f, 0.f, 0.f};
        #pragma unroll
        for (int kw = 0; kw < 16; ++kw) {
            const int kg = kw * 4 + l16;          // 0..63
            const int off = lrow * 1024 + ((kg ^ (lrow & 7)) << 4);
            const bf16x8 a_h = *(const bf16x8*)((const char*)hH + off);
            const bf16x8 a_l = *(const bf16x8*)((const char*)hL + off);
            const size_t bo = ((size_t)kg * 2048 + gcol) * 8;
            const bf16x8 b_h = *(const bf16x8*)(BkH + bo);
            const bf16x8 b_l = *(const bf16x8*)(BkL + bo);
            acc = __builtin_amdgcn_mfma_f32_16x16x32_bf16(a_h, b_h, acc, 0, 0, 0);
            acc = __builtin_amdgcn_mfma_f32_16x16x32_bf16(a_h, b_l, acc, 0, 0, 0);
            acc = __builtin_amdgcn_mfma_f32_16x16x32_bf16(a_l, b_h, acc, 0, 0, 0);
        }
        const float bb = (gcol < 1024) ? dfB[gcol] : dbB[gcol - 1024];
        float* xp = xw + (size_t)(g * 32 + mh * 16 + l16 * 4) * 2048 + gcol;
        #pragma unroll
        for (int r = 0; r < 4; ++r) xp[2048 * r] = acc[r] + bb;
    }
    __syncthreads();                              // proj reads of hH done
    {   // zero h for decoder
        const uint4 z4{0u, 0u, 0u, 0u};
        for (int i = tid; i < 2048; i += 512) { ((uint4*)hH)[i] = z4; ((uint4*)hL)[i] = z4; }
    }
    float cd[16];
    #pragma unroll
    for (int j = 0; j < 16; ++j) cd[j] = 0.f;
    gbar2(encCnt, encGen, 32, ++bcE);             // xw ready (drains writes)

    // =====================================================================
    // decoder: 64 steps, dir-split (fan 16). Block w: dir = w>>4.
    // =====================================================================
    const int ddir = w >> 4, dw = w & 15;
    unsigned* dCnt = barg + 64 + ddir * 64;
    unsigned* dGen = barg + 96 + ddir * 64;
    for (int s = 0; s < 64; ++s) {
        float* zc = zb + (unsigned)(s & 1) * 524288u;
        {   // ---- GEMM: z[32 rows][my 64 cols] = h_dir @ Bdu (K=256) ----
            f32x4 acc = {0.f, 0.f, 0.f, 0.f};
            #pragma unroll
            for (int kw = 0; kw < 8; ++kw) {
                const int kg = kw * 4 + l16;      // 0..31
                const int blk = ddir * 32 + kg;
                const int off = lrow * 1024 + ((blk ^ (lrow & 7)) << 4);
                const bf16x8 a_h = *(const bf16x8*)((const char*)hH + off);
                const bf16x8 a_l = *(const bf16x8*)((const char*)hL + off);
                const size_t bo = ((size_t)kg * 2048 + gcol) * 8;
                const bf16x8 b_h = *(const bf16x8*)(BuH + bo);
                const bf16x8 b_l = *(const bf16x8*)(BuL + bo);
                acc = __builtin_amdgcn_mfma_f32_16x16x32_bf16(a_h, b_h, acc, 0, 0, 0);
                acc = __builtin_amdgcn_mfma_f32_16x16x32_bf16(a_h, b_l, acc, 0, 0, 0);
                acc = __builtin_amdgcn_mfma_f32_16x16x32_bf16(a_l, b_h, acc, 0, 0, 0);
            }
            float* zp = zc + (size_t)(g * 32 + mh * 16 + l16 * 4) * 2048 + gcol;
            #pragma unroll
            for (int r = 0; r < 4; ++r) zp[2048 * r] = acc[r];
        }
        gbar2(dCnt, dGen, 16, ++bcD);

        // ---- redundant update (own dir): 16 units/thread; h -> LDS ----
        {
            const float* zr = zc + (size_t)(g * 32 + urow) * 2048 + ddir * 1024;
            const float* xr = xw + (size_t)(g * 32 + urow) * 2048 + ddir * 1024;
            const int du0 = uch * 16;             // dir-local unit base
            const int tt = ddir ? (63 - s) : s;
            const bool shareW = (uch == dw);      // this thread writes hseq
            unsigned short* hsp = hseqb + ((size_t)(g * 32 + urow) * 64 + tt) * 512
                                + ddir * 256 + du0;
            #pragma unroll
            for (int jj = 0; jj < 4; ++jj) {
                const float4 zi4 = *(const float4*)(zr + du0 + jj * 4);
                const float4 xi4 = *(const float4*)(xr + du0 + jj * 4);
                const float4 zf4 = *(const float4*)(zr + 256 + du0 + jj * 4);
                const float4 xf4 = *(const float4*)(xr + 256 + du0 + jj * 4);
                const float4 zg4 = *(const float4*)(zr + 512 + du0 + jj * 4);
                const float4 xg4 = *(const float4*)(xr + 512 + du0 + jj * 4);
                const float4 zo4 = *(const float4*)(zr + 768 + du0 + jj * 4);
                const float4 xo4 = *(const float4*)(xr + 768 + du0 + jj * 4);
                const float zi_[4] = {zi4.x + xi4.x, zi4.y + xi4.y, zi4.z + xi4.z, zi4.w + xi4.w};
                const float zf_[4] = {zf4.x + xf4.x, zf4.y + xf4.y, zf4.z + xf4.z, zf4.w + xf4.w};
                const float zg_[4] = {zg4.x + xg4.x, zg4.y + xg4.y, zg4.z + xg4.z, zg4.w + xg4.w};
                const float zo_[4] = {zo4.x + xo4.x, zo4.y + xo4.y, zo4.z + xo4.z, zo4.w + xo4.w};
                #pragma unroll
                for (int p2 = 0; p2 < 2; ++p2) {
                    const int k0 = p2 * 2;
                    const int j0 = jj * 4 + k0;
                    const float cv0 = sigm(zf_[k0])   * cd[j0]   + sigm(zi_[k0])   * tanhf(zg_[k0]);
                    const float cv1 = sigm(zf_[k0+1]) * cd[j0+1] + sigm(zi_[k0+1]) * tanhf(zg_[k0+1]);
                    cd[j0] = cv0; cd[j0+1] = cv1;
                    const float h0 = sigm(zo_[k0])   * tanhf(cv0);
                    const float h1 = sigm(zo_[k0+1]) * tanhf(cv1);
                    unsigned short h0h, h0l, h1h, h1l;
                    split2(h0, h0h, h0l); split2(h1, h1h, h1l);
                    const int u = ddir * 256 + du0 + j0;     // global unit (even)
                    const int off = urow * 1024 + (((u >> 3) ^ (urow & 7)) << 4) + (u & 7) * 2;
                    *(unsigned*)((char*)hH + off) = (unsigned)h0h | ((unsigned)h1h << 16);
                    *(unsigned*)((char*)hL + off) = (unsigned)h0l | ((unsigned)h1l << 16);
                    if (shareW)
                        *(unsigned*)(hsp + j0) = (unsigned)h0h | ((unsigned)h1h << 16);
                }
            }
        }
        __syncthreads();   // h writes visible before next GEMM
    }
    gbar2(encCnt, encGen, 32, ++bcE);             // hseq complete (both dirs)

    // =====================================================================
    // dense head: block -> batch row (g*32+w), all 64 t: 64 bt rows
    // =====================================================================
    {
        float* dkc = (float*)hH;                  // 32 KB, h no longer needed
        for (int i = tid; i < 8192; i += 512) dkc[i] = dK[i];
        __syncthreads();
        const int f = tid & 15;
        #pragma unroll
        for (int p = 0; p < 2; ++p) {
            const int bt = g * 2048 + w * 64 + (tid >> 4) + p * 32;
            const unsigned short* hs = hseqb + (size_t)bt * 512;
            float acc = dnB[f];
            #pragma unroll 4
            for (int k = 0; k < 512; k += 8) {
                const u16x8 hv = *(const u16x8*)(hs + k);
                #pragma unroll
                for (int j = 0; j < 8; ++j)
                    acc += bf2f(hv[j]) * dkc[(k + j) * 16 + f];
            }
            out[(size_t)bt * 16 + f] = acc;
        }
    }
}

// ---------------------------------------------------------------------------
extern "C" void kernel_launch(void* const* d_in, const int* in_sizes, int n_in,
                              void* d_out, int out_size, void* d_ws, size_t ws_size,
                              hipStream_t stream)
{
    const float* x    = (const float*)d_in[0];
    const float* encW = (const float*)d_in[1];
    const float* encU = (const float*)d_in[2];
    const float* encB = (const float*)d_in[3];
    const float* dfK  = (const float*)d_in[4];
    const float* dfU  = (const float*)d_in[5];
    const float* dfB  = (const float*)d_in[6];
    const float* dbK  = (const float*)d_in[7];
    const float* dbU  = (const float*)d_in[8];
    const float* dbB  = (const float*)d_in[9];
    const float* dK   = (const float*)d_in[10];
    const float* dnB  = (const float*)d_in[11];

    if (ws_size < WS_FLOATS * sizeof(float)) return;

    float* ws = (float*)d_ws;
    unsigned short* BencH = (unsigned short*)(ws + OFS_BENCH);
    unsigned short* BencL = (unsigned short*)(ws + OFS_BENCL);
    unsigned short* BdkH  = (unsigned short*)(ws + OFS_BDKH);
    unsigned short* BdkL  = (unsigned short*)(ws + OFS_BDKL);
    unsigned short* BduH  = (unsigned short*)(ws + OFS_BDUH);
    unsigned short* BduL  = (unsigned short*)(ws + OFS_BDUL);
    unsigned* bar = (unsigned*)(ws + OFS_BAR);

    // one-time weight packs (pack_b<0> re-inits all barrier words per replay)
    pack_b<0><<<576, 256, 0, stream>>>(encW, encU, BencH, BencL, bar);
    pack_b<1><<<512, 256, 0, stream>>>(dfK, dbK, BdkH, BdkL, nullptr);
    pack_b<2><<<256, 256, 0, stream>>>(dfU, dbU, BduH, BduL, nullptr);

    // persistent kernel: whole network, XCD-local sync only
    lstm_all<<<256, 512, 0, stream>>>(x, encB, dfB, dbB, dK, dnB,
                                      (float*)d_out, ws);
}

// Round 9
// 3918.917 us; speedup vs baseline: 1.4505x; 1.4505x over previous
//
#include <hip/hip_runtime.h>
#include <math.h>

// ---------------------------------------------------------------------------
// LSTM encoder-decoder, 3-term bf16 MFMA (hi/lo split), persistent kernel.
// 8 XCD-local groups (bid&7), 32 blocks x 512 thr each, own 32 batch rows.
// GATE-GROUPED columns: block w owns 4 gates x 16 units -> z stays in-block
// (registers -> LDS zt); only softmax (max,sum) partials cross blocks (8KB).
// 3 dataflow syncs per enc step (stats-g, stats-c, h-ready), 1 per dec step.
// Sync primitive (r7-proven): vmcnt drain + 1 relaxed RMW arrive on monotonic
// counter + relaxed-load poll + buffer_inv sc0 (L1-only). No L2 flushes.
// B_hi in LDS (64KB, r7-proven L2 regime); c-state = 1 register/thread.
// ---------------------------------------------------------------------------

typedef __attribute__((ext_vector_type(8))) short bf16x8;
typedef __attribute__((ext_vector_type(8))) unsigned short u16x8;
typedef __attribute__((ext_vector_type(4))) float f32x4;

// ws layout (float offsets)
#define OFS_XW     0u          // 256*2048 f32 (gate-grouped, block-self-consumed)
#define OFS_HEH    524288u     // enc h hi: 256*512 bf16 (=65536 f)
#define OFS_HEL    589824u
#define OFS_HD     655360u     // dec h: [par2][dir2][hi/lo][256*256 bf16=32768f]
#define OFS_HSEQ   917504u     // 256*64*512 bf16 (=4194304 f)
#define OFS_BENCH  5111808u    // 72*2048*8 bf16 packed (gate-grouped cols)
#define OFS_BENCL  5701632u
#define OFS_BDKH   6291456u    // 64*2048*8
#define OFS_BDKL   6815744u
#define OFS_BDUH   7340032u    // 32*2048*8
#define OFS_BDUL   7602176u
#define OFS_PST    7864320u    // pst1: 8g*32row*32w*2f =16384; pst2: +16384
#define OFS_BAR    7897088u    // 2048 u32: group g at [g*256]
#define WS_FLOATS  7899136u    // ~31.6 MB

__device__ __forceinline__ unsigned short bf_hi(float f) {
    union { float f; unsigned u; } v; v.f = f;
    unsigned r = v.u + 0x7fffu + ((v.u >> 16) & 1u);
    return (unsigned short)(r >> 16);
}
__device__ __forceinline__ float bf2f(unsigned short h) {
    union { unsigned u; float f; } v; v.u = ((unsigned)h) << 16;
    return v.f;
}
__device__ __forceinline__ void split2(float f, unsigned short& hi, unsigned short& lo) {
    hi = bf_hi(f);
    lo = bf_hi(f - bf2f(hi));
}
__device__ __forceinline__ float sigm(float x) { return 1.0f / (1.0f + __expf(-x)); }

// ---- dataflow sync primitives (monotonic counter, XCD-local) --------------
__device__ __forceinline__ void arrive(unsigned* w) {
    asm volatile("s_waitcnt vmcnt(0) lgkmcnt(0)" ::: "memory");  // per-wave drain
    __syncthreads();
    if (threadIdx.x == 0)
        __hip_atomic_fetch_add(w, 1u, __ATOMIC_RELAXED, __HIP_MEMORY_SCOPE_AGENT);
}
__device__ __forceinline__ void waitge(unsigned* w, unsigned tgt) {
    if (threadIdx.x == 0) {
        const long long t0 = clock64();
        while (__hip_atomic_load(w, __ATOMIC_RELAXED,
                                 __HIP_MEMORY_SCOPE_AGENT) < tgt) {
            __builtin_amdgcn_s_sleep(1);
            asm volatile("buffer_inv sc0" ::: "memory");
            if (clock64() - t0 > 2000000LL) break;   // deadlock guard (~0.8ms)
        }
        asm volatile("buffer_inv sc0" ::: "memory"); // L1 invalidate only
    }
    __syncthreads();
}

// 16-lane-span reductions (xor masks 1..8 stay inside a 16-lane row span)
__device__ __forceinline__ float red16max(float v) {
    #pragma unroll
    for (int m = 8; m; m >>= 1) v = fmaxf(v, __shfl_xor(v, m, 64));
    return v;
}
__device__ __forceinline__ float red16sum(float v) {
    #pragma unroll
    for (int m = 8; m; m >>= 1) v += __shfl_xor(v, m, 64);
    return v;
}

// ---------------------------------------------------------------------------
// weight pack: fp32 -> bf16 hi/lo, frag layout [kg][2048 packed cols][8]
// GATE-GROUPED packed col n: w=n>>6, gate=(n>>4)&3, ul=n&15.
// MODE 0 (enc, 72 kg): src col = gate*512 + w*16 + ul; rows: k<64 encW else encU
// MODE 1 (dec kernel, 64 kg): dir=n>>10, bw=(n>>6)&15; src = gate*256+bw*16+ul
// MODE 2 (dec rec, 32 kg): same col map as MODE 1
// MODE 0 also zero-initializes the 2048 barrier words (replay-safe).
// ---------------------------------------------------------------------------
template <int MODE>
__global__ __launch_bounds__(256) void pack_b(
    const float* __restrict__ S0, const float* __restrict__ S1,
    unsigned short* __restrict__ H, unsigned short* __restrict__ L,
    unsigned* __restrict__ bar)
{
    if (MODE == 0 && blockIdx.x < 8) bar[blockIdx.x * 256 + threadIdx.x] = 0u;
    const int idx = blockIdx.x * 256 + threadIdx.x;
    const int n = idx & 2047, kg = idx >> 11;
    int sc;
    const float* Sd;
    if (MODE == 0) {
        sc = ((n >> 4) & 3) * 512 + (n >> 6) * 16 + (n & 15);
        Sd = nullptr;
    } else {
        const int dir = n >> 10, bw = (n >> 6) & 15;
        sc = ((n >> 4) & 3) * 256 + bw * 16 + (n & 15);
        Sd = dir ? S1 : S0;
    }
    u16x8 h8, l8;
    #pragma unroll
    for (int j = 0; j < 8; ++j) {
        const int k = kg * 8 + j;
        float v;
        if (MODE == 0) v = (k < 64) ? S0[(size_t)k * 2048 + sc] : S1[(size_t)(k - 64) * 2048 + sc];
        else           v = Sd[(size_t)k * 1024 + sc];
        unsigned short hh, ll; split2(v, hh, ll);
        h8[j] = hh; l8[j] = ll;
    }
    *(u16x8*)(H + (size_t)idx * 8) = h8;
    *(u16x8*)(L + (size_t)idx * 8) = l8;
}

// ===========================================================================
// Persistent kernel. 256 blocks x 512 thr (8 waves), LDS ~74KB -> 2/CU
// capacity (32 blocks/XCD need <=32 of 64 slots: slack). g=bid&7, w=bid>>3.
// ===========================================================================
__global__ __launch_bounds__(512, 2) void lstm_all(
    const float* __restrict__ x, const float* __restrict__ encB,
    const float* __restrict__ dfB, const float* __restrict__ dbB,
    const float* __restrict__ dK, const float* __restrict__ dnB,
    float* __restrict__ out, float* __restrict__ ws)
{
    const int bid = blockIdx.x, tid = threadIdx.x;
    const int g = bid & 7, w = bid >> 3;          // group (XCD), slot 0..31
    const int lane = tid & 63, wid = tid >> 6;
    const int mh = wid & 1, nh = wid >> 1;        // 2 x 4 wave grid; nh = gate
    const int l16 = lane >> 4, lr = lane & 15;
    const int lrow = mh * 16 + lr;                // local A row
    const int grow = g * 32 + lrow;               // global batch row
    const int ncl  = nh * 16 + lr;                // block-local col 0..63
    const int gcolp = w * 64 + ncl;               // packed global col
    const int urow = tid >> 4, ul = tid & 15;     // update ids: row, unit

    float* xw = ws + OFS_XW;
    unsigned short* hEHu = (unsigned short*)(ws + OFS_HEH);
    unsigned short* hELu = (unsigned short*)(ws + OFS_HEL);
    unsigned short* hseqb = (unsigned short*)(ws + OFS_HSEQ);
    const unsigned short* BeH = (const unsigned short*)(ws + OFS_BENCH);
    const unsigned short* BeL = (const unsigned short*)(ws + OFS_BENCL);
    const unsigned short* BkH = (const unsigned short*)(ws + OFS_BDKH);
    const unsigned short* BkL = (const unsigned short*)(ws + OFS_BDKL);
    const unsigned short* BuH = (const unsigned short*)(ws + OFS_BDUH);
    const unsigned short* BuL = (const unsigned short*)(ws + OFS_BDUL);
    float* pst1 = ws + OFS_PST + (unsigned)g * 2048u;
    float* pst2 = ws + OFS_PST + 16384u + (unsigned)g * 2048u;
    unsigned* barg = (unsigned*)(ws + OFS_BAR) + g * 256;
    unsigned* cntA = barg + 0;
    unsigned* cntB = barg + 32;
    unsigned* cntC = barg + 64;
    unsigned* cntE = barg + 160;

    // LDS: B_hi slice (enc kg 8..71: 64kg x 64col x 8 = 64KB) + zt [64][33]
    __shared__ __align__(16) unsigned short sBe[32768];
    __shared__ __align__(16) float zt[2112];

    // dec h pointers [par][hi/lo] for this block's dir (set later)
    const int dir = w >> 4, bw = w & 15;
    unsigned short* hd[2][2];
    #pragma unroll
    for (int p = 0; p < 2; ++p)
        #pragma unroll
        for (int hl_ = 0; hl_ < 2; ++hl_)
            hd[p][hl_] = (unsigned short*)(ws + OFS_HD +
                          (unsigned)((p * 2 + dir) * 2 + hl_) * 32768u);

    // ---- init: zero own h slices (enc + dec both parities) ----
    {
        const size_t he = (size_t)(g * 32 + urow) * 512 + w * 16 + ul;
        hEHu[he] = 0; hELu[he] = 0;
        const size_t hdix = (size_t)(g * 32 + urow) * 256 + bw * 16 + ul;
        #pragma unroll
        for (int p = 0; p < 2; ++p) { hd[p][0][hdix] = 0; hd[p][1][hdix] = 0; }
    }
    // ---- load enc B_hi (kg 8..71, own 64 cols) into LDS ----
    for (int i = tid; i < 4096; i += 512) {       // i = kg8*64 + nc
        const int kg8 = i >> 6, nc = i & 63;
        *(u16x8*)(sBe + i * 8) =
            *(const u16x8*)(BeH + ((size_t)(kg8 + 8) * 2048 + w * 64 + nc) * 8);
    }
    arrive(cntC);                                  // cntC = 32 after init

    const float encBias = encB[nh * 512 + w * 16 + lr];
    float c = 0.f;                                 // enc c-state: 1 reg/thread

    // =====================================================================
    // encoder: 256 steps, 3 dataflow syncs each
    // =====================================================================
    for (int t = 0; t < 256; ++t) {
        waitge(cntC, 32u * (t + 1));               // h(t-1) ready
        // ---- GEMM: z[32 rows][own 64 gate-grouped cols], K=576 ----
        f32x4 acc = {0.f, 0.f, 0.f, 0.f};
        #pragma unroll
        for (int kw = 0; kw < 18; ++kw) {
            const int kg = kw * 4 + l16;
            bf16x8 a_h, a_l;
            if (kw < 2) {                          // x part, fp32 -> hi/lo
                const float* xp = x + (size_t)grow * 16384 + t * 64 + kg * 8;
                const float4 x0 = *(const float4*)xp;
                const float4 x1 = *(const float4*)(xp + 4);
                const float xs[8] = {x0.x, x0.y, x0.z, x0.w, x1.x, x1.y, x1.z, x1.w};
                #pragma unroll
                for (int j = 0; j < 8; ++j) {
                    unsigned short hh, ll; split2(xs[j], hh, ll);
                    a_h[j] = (short)hh; a_l[j] = (short)ll;
                }
            } else {                               // h part (global, L2)
                const size_t ao = (size_t)grow * 512 + (size_t)(kg - 8) * 8;
                a_h = *(const bf16x8*)(hEHu + ao);
                a_l = *(const bf16x8*)(hELu + ao);
            }
            bf16x8 b_h;
            if (kw < 2) b_h = *(const bf16x8*)(BeH + ((size_t)kg * 2048 + gcolp) * 8);
            else        b_h = *(const bf16x8*)(sBe + ((kg - 8) * 64 + ncl) * 8);
            const bf16x8 b_l = *(const bf16x8*)(BeL + ((size_t)kg * 2048 + gcolp) * 8);
            acc = __builtin_amdgcn_mfma_f32_16x16x32_bf16(a_h, b_h, acc, 0, 0, 0);
            acc = __builtin_amdgcn_mfma_f32_16x16x32_bf16(a_h, b_l, acc, 0, 0, 0);
            acc = __builtin_amdgcn_mfma_f32_16x16x32_bf16(a_l, b_h, acc, 0, 0, 0);
        }
        #pragma unroll
        for (int r = 0; r < 4; ++r)
            zt[ncl * 33 + mh * 16 + l16 * 4 + r] = acc[r] + encBias;
        __syncthreads();

        // ---- stats-g partials (thread = (urow, ul): one (row, unit)) ----
        const float zg = zt[(32 + ul) * 33 + urow];
        {
            const float mw = red16max(zg);
            const float sw = red16sum(__expf(zg - mw));
            if (ul == 0) *(float2*)(pst1 + (urow * 32 + w) * 2) = float2{mw, sw};
        }
        arrive(cntA); waitge(cntA, 32u * (t + 1));

        // ---- combine g-stats; c update ----
        float M, S;
        {
            const float2 pa = *(const float2*)(pst1 + (urow * 32 + ul) * 2);
            const float2 pb = *(const float2*)(pst1 + (urow * 32 + ul + 16) * 2);
            const float ml = fmaxf(pa.x, pb.x);
            const float sl = pa.y * __expf(pa.x - ml) + pb.y * __expf(pb.x - ml);
            M = red16max(ml);
            S = red16sum(sl * __expf(ml - M));
        }
        const float zi = zt[ul * 33 + urow];
        const float zf = zt[(16 + ul) * 33 + urow];
        c = sigm(zf) * c + sigm(zi) * (__expf(zg - M) / S);

        // ---- stats-c partials ----
        {
            const float m2 = red16max(c);
            const float s2 = red16sum(__expf(c - m2));
            if (ul == 0) *(float2*)(pst2 + (urow * 32 + w) * 2) = float2{m2, s2};
        }
        arrive(cntB); waitge(cntB, 32u * (t + 1));

        // ---- combine c-stats; h write (own 16-unit slice only) ----
        {
            const float2 pa = *(const float2*)(pst2 + (urow * 32 + ul) * 2);
            const float2 pb = *(const float2*)(pst2 + (urow * 32 + ul + 16) * 2);
            const float ml = fmaxf(pa.x, pb.x);
            const float sl = pa.y * __expf(pa.x - ml) + pb.y * __expf(pb.x - ml);
            const float M2 = red16max(ml);
            const float S2 = red16sum(sl * __expf(ml - M2));
            const float zo = zt[(48 + ul) * 33 + urow];
            const float hv = sigm(zo) * __expf(c - M2) / S2;
            unsigned short hh, hl; split2(hv, hh, hl);
            const size_t he = (size_t)(g * 32 + urow) * 512 + w * 16 + ul;
            hEHu[he] = hh;
            hELu[he] = hl;
        }
        arrive(cntC);
    }
    waitge(cntC, 32u * 257u);                      // final h complete

    // =====================================================================
    // decoder input projection: xw[rows][own 64 cols] (self-consumed!)
    // =====================================================================
    {
        const float bias = (dir ? dbB : dfB)[nh * 256 + bw * 16 + lr];
        f32x4 acc = {0.f, 0.f, 0.f, 0.f};
        #pragma unroll
        for (int kw = 0; kw < 16; ++kw) {
            const int kg = kw * 4 + l16;           // 0..63
            const size_t ao = (size_t)grow * 512 + (size_t)kg * 8;
            const bf16x8 a_h = *(const bf16x8*)(hEHu + ao);
            const bf16x8 a_l = *(const bf16x8*)(hELu + ao);
            const size_t bo = ((size_t)kg * 2048 + gcolp) * 8;
            const bf16x8 b_h = *(const bf16x8*)(BkH + bo);
            const bf16x8 b_l = *(const bf16x8*)(BkL + bo);
            acc = __builtin_amdgcn_mfma_f32_16x16x32_bf16(a_h, b_h, acc, 0, 0, 0);
            acc = __builtin_amdgcn_mfma_f32_16x16x32_bf16(a_h, b_l, acc, 0, 0, 0);
            acc = __builtin_amdgcn_mfma_f32_16x16x32_bf16(a_l, b_h, acc, 0, 0, 0);
        }
        float* xp = xw + (size_t)(g * 32 + mh * 16 + l16 * 4) * 2048 + gcolp;
        #pragma unroll
        for (int r = 0; r < 4; ++r) xp[2048 * r] = acc[r] + bias;
    }
    asm volatile("s_waitcnt vmcnt(0)" ::: "memory");
    __syncthreads();                               // xw visible block-locally

    // ---- load dec B_hi (32 kg x own 64 cols) into LDS ----
    for (int i = tid; i < 2048; i += 512) {        // i = kg*64 + nc
        const int kg = i >> 6, nc = i & 63;
        *(u16x8*)(sBe + i * 8) =
            *(const u16x8*)(BuH + ((size_t)kg * 2048 + w * 64 + nc) * 8);
    }
    __syncthreads();

    // =====================================================================
    // decoder: 64 steps, 1 sync each (per-dir, fan 16); h parity dbuf
    // =====================================================================
    unsigned* cntD = barg + 96 + dir * 32;
    float cd = 0.f;
    const float* xr = xw + (size_t)(g * 32 + urow) * 2048 + w * 64;
    for (int s = 0; s < 64; ++s) {
        if (s) waitge(cntD, 16u * s);              // h(s-1) ready
        const int par = s & 1;
        f32x4 acc = {0.f, 0.f, 0.f, 0.f};
        #pragma unroll
        for (int kw = 0; kw < 8; ++kw) {
            const int kg = kw * 4 + l16;           // 0..31
            const size_t ao = (size_t)(g * 32 + lrow) * 256 + (size_t)kg * 8;
            const bf16x8 a_h = *(const bf16x8*)(hd[par][0] + ao);
            const bf16x8 a_l = *(const bf16x8*)(hd[par][1] + ao);
            const bf16x8 b_h = *(const bf16x8*)(sBe + (kg * 64 + ncl) * 8);
            const bf16x8 b_l = *(const bf16x8*)(BuL + ((size_t)kg * 2048 + gcolp) * 8);
            acc = __builtin_amdgcn_mfma_f32_16x16x32_bf16(a_h, b_h, acc, 0, 0, 0);
            acc = __builtin_amdgcn_mfma_f32_16x16x32_bf16(a_h, b_l, acc, 0, 0, 0);
            acc = __builtin_amdgcn_mfma_f32_16x16x32_bf16(a_l, b_h, acc, 0, 0, 0);
        }
        #pragma unroll
        for (int r = 0; r < 4; ++r)
            zt[ncl * 33 + mh * 16 + l16 * 4 + r] = acc[r];
        __syncthreads();

        {   // ---- elementwise gate update: thread owns (urow, unit ul) ----
            const float zi = zt[ul * 33 + urow]        + xr[ul];
            const float zf = zt[(16 + ul) * 33 + urow] + xr[16 + ul];
            const float zg = zt[(32 + ul) * 33 + urow] + xr[32 + ul];
            const float zo = zt[(48 + ul) * 33 + urow] + xr[48 + ul];
            const float cv = sigm(zf) * cd + sigm(zi) * tanhf(zg);
            cd = cv;
            const float hv = sigm(zo) * tanhf(cv);
            unsigned short hh, hl; split2(hv, hh, hl);
            const size_t hdix = (size_t)(g * 32 + urow) * 256 + bw * 16 + ul;
            hd[par ^ 1][0][hdix] = hh;
            hd[par ^ 1][1][hdix] = hl;
            const int tt = dir ? (63 - s) : s;
            hseqb[((size_t)(g * 32 + urow) * 64 + tt) * 512 + dir * 256 + bw * 16 + ul] = hh;
        }
        arrive(cntD);
    }
    arrive(cntE); waitge(cntE, 32u);               // hseq complete (both dirs)

    // =====================================================================
    // dense head: block w -> 64 bt rows of this group's 2048
    // =====================================================================
    {
        float* dkc = (float*)sBe;                  // 32 KB dK cache
        for (int i = tid; i < 8192; i += 512) dkc[i] = dK[i];
        __syncthreads();
        const int f = tid & 15;
        #pragma unroll
        for (int p = 0; p < 2; ++p) {
            const int bt = g * 2048 + w * 64 + (tid >> 4) + p * 32;
            const unsigned short* hs = hseqb + (size_t)bt * 512;
            float acc = dnB[f];
            #pragma unroll 4
            for (int k = 0; k < 512; k += 8) {
                const u16x8 hv = *(const u16x8*)(hs + k);
                #pragma unroll
                for (int j = 0; j < 8; ++j)
                    acc += bf2f(hv[j]) * dkc[(k + j) * 16 + f];
            }
            out[(size_t)bt * 16 + f] = acc;
        }
    }
}

// ---------------------------------------------------------------------------
extern "C" void kernel_launch(void* const* d_in, const int* in_sizes, int n_in,
                              void* d_out, int out_size, void* d_ws, size_t ws_size,
                              hipStream_t stream)
{
    const float* x    = (const float*)d_in[0];
    const float* encW = (const float*)d_in[1];
    const float* encU = (const float*)d_in[2];
    const float* encB = (const float*)d_in[3];
    const float* dfK  = (const float*)d_in[4];
    const float* dfU  = (const float*)d_in[5];
    const float* dfB  = (const float*)d_in[6];
    const float* dbK  = (const float*)d_in[7];
    const float* dbU  = (const float*)d_in[8];
    const float* dbB  = (const float*)d_in[9];
    const float* dK   = (const float*)d_in[10];
    const float* dnB  = (const float*)d_in[11];

    if (ws_size < WS_FLOATS * sizeof(float)) return;

    float* ws = (float*)d_ws;
    unsigned short* BencH = (unsigned short*)(ws + OFS_BENCH);
    unsigned short* BencL = (unsigned short*)(ws + OFS_BENCL);
    unsigned short* BdkH  = (unsigned short*)(ws + OFS_BDKH);
    unsigned short* BdkL  = (unsigned short*)(ws + OFS_BDKL);
    unsigned short* BduH  = (unsigned short*)(ws + OFS_BDUH);
    unsigned short* BduL  = (unsigned short*)(ws + OFS_BDUL);
    unsigned* bar = (unsigned*)(ws + OFS_BAR);

    // one-time weight packs (pack_b<0> re-inits all barrier words per replay)
    pack_b<0><<<576, 256, 0, stream>>>(encW, encU, BencH, BencL, bar);
    pack_b<1><<<512, 256, 0, stream>>>(dfK, dbK, BdkH, BdkL, nullptr);
    pack_b<2><<<256, 256, 0, stream>>>(dfU, dbU, BduH, BduL, nullptr);

    // persistent kernel: whole network, XCD-local dataflow sync only
    lstm_all<<<256, 512, 0, stream>>>(x, encB, dfB, dbB, dK, dnB,
                                      (float*)d_out, ws);
}